// Round 2
// baseline (603.680 us; speedup 1.0000x reference)
//
#include <hip/hip_runtime.h>

#define NBQ 12544
#define DM  256
#define MM  2048

typedef __attribute__((ext_vector_type(8)))  __bf16 bf16x8;
typedef __attribute__((ext_vector_type(4)))  float  floatx4;

__device__ __forceinline__ ushort f2bf(float x) {
    unsigned u = __float_as_uint(x);
    u += 0x7fffu + ((u >> 16) & 1u);   // RNE
    return (ushort)(u >> 16);
}
__device__ __forceinline__ float bf2f(ushort h) {
    return __uint_as_float(((unsigned)h) << 16);
}

// ---------- projections, weight-pairs folded (r11/r12/r13-proven) ----------
__global__ __launch_bounds__(256) void gemm_proj_all(
    const float* __restrict__ x,      const float* __restrict__ ch_mem,
    const float* __restrict__ ch_wq,  const float* __restrict__ ch_wk,
    const float* __restrict__ ch_wv,  const float* __restrict__ sp_mem,
    const float* __restrict__ sp_wq,  const float* __restrict__ sp_wk,
    const float* __restrict__ sp_wv,
    ushort* __restrict__ Qb,  ushort* __restrict__ QFb,
    ushort* __restrict__ Kb,  ushort* __restrict__ KFb,
    ushort* __restrict__ Vtb, ushort* __restrict__ VFtb)
{
    __shared__ ushort As[64][72];
    __shared__ ushort W1s[64][72];
    __shared__ ushort W2s[64][72];

    int bid = blockIdx.x;
    const float* A; const float* W1; const float* W2;
    ushort* C1; ushort* C2; int nrows, trans2;
    if (bid < 784) {
        A = x; W1 = ch_wq; W2 = sp_wq; C1 = Qb; C2 = QFb; nrows = NBQ; trans2 = 0;
    } else if (bid < 912) {
        A = ch_mem; W1 = ch_wk; W2 = ch_wv; C1 = Kb; C2 = Vtb;
        nrows = MM; trans2 = 1; bid -= 784;
    } else {
        A = sp_mem; W1 = sp_wk; W2 = sp_wv; C1 = KFb; C2 = VFtb;
        nrows = MM; trans2 = 1; bid -= 912;
    }
    const int r0 = (bid >> 2) * 64;
    const int c0 = (bid & 3) * 64;

    const int tid  = threadIdx.x;
    const int wv   = tid >> 6;
    const int lane = tid & 63;
    const int quad = lane >> 4;
    const int l16  = lane & 15;
    const int rw = (wv & 1) * 32;
    const int cw = (wv >> 1) * 32;

    floatx4 acc1[2][2], acc2[2][2];
    #pragma unroll
    for (int i = 0; i < 2; ++i)
        #pragma unroll
        for (int j = 0; j < 2; ++j) {
            acc1[i][j] = (floatx4){0.f, 0.f, 0.f, 0.f};
            acc2[i][j] = (floatx4){0.f, 0.f, 0.f, 0.f};
        }

    for (int d0 = 0; d0 < 256; d0 += 64) {
        __syncthreads();
        #pragma unroll
        for (int it = 0; it < 4; ++it) {
            int idx = tid + it * 256;
            int r = idx >> 4, c4 = (idx & 15) * 4;
            float4 a4 = *(const float4*)(A  + (size_t)(r0 + r) * 256 + d0 + c4);
            float4 w14 = *(const float4*)(W1 + (size_t)(c0 + r) * 256 + d0 + c4);
            float4 w24 = *(const float4*)(W2 + (size_t)(c0 + r) * 256 + d0 + c4);
            ushort4 ab, w1b, w2b;
            ab.x = f2bf(a4.x);  ab.y = f2bf(a4.y);  ab.z = f2bf(a4.z);  ab.w = f2bf(a4.w);
            w1b.x = f2bf(w14.x); w1b.y = f2bf(w14.y); w1b.z = f2bf(w14.z); w1b.w = f2bf(w14.w);
            w2b.x = f2bf(w24.x); w2b.y = f2bf(w24.y); w2b.z = f2bf(w24.z); w2b.w = f2bf(w24.w);
            *(ushort4*)&As[r][c4]  = ab;
            *(ushort4*)&W1s[r][c4] = w1b;
            *(ushort4*)&W2s[r][c4] = w2b;
        }
        __syncthreads();
        #pragma unroll
        for (int kk = 0; kk < 64; kk += 32) {
            bf16x8 aA0 = *(const bf16x8*)&As[rw + l16][kk + quad * 8];
            bf16x8 aA1 = *(const bf16x8*)&As[rw + 16 + l16][kk + quad * 8];
            bf16x8 b10 = *(const bf16x8*)&W1s[cw + l16][kk + quad * 8];
            bf16x8 b11 = *(const bf16x8*)&W1s[cw + 16 + l16][kk + quad * 8];
            bf16x8 b20 = *(const bf16x8*)&W2s[cw + l16][kk + quad * 8];
            bf16x8 b21 = *(const bf16x8*)&W2s[cw + 16 + l16][kk + quad * 8];
            acc1[0][0] = __builtin_amdgcn_mfma_f32_16x16x32_bf16(aA0, b10, acc1[0][0], 0, 0, 0);
            acc1[0][1] = __builtin_amdgcn_mfma_f32_16x16x32_bf16(aA0, b11, acc1[0][1], 0, 0, 0);
            acc1[1][0] = __builtin_amdgcn_mfma_f32_16x16x32_bf16(aA1, b10, acc1[1][0], 0, 0, 0);
            acc1[1][1] = __builtin_amdgcn_mfma_f32_16x16x32_bf16(aA1, b11, acc1[1][1], 0, 0, 0);
            acc2[0][0] = __builtin_amdgcn_mfma_f32_16x16x32_bf16(aA0, b20, acc2[0][0], 0, 0, 0);
            acc2[0][1] = __builtin_amdgcn_mfma_f32_16x16x32_bf16(aA0, b21, acc2[0][1], 0, 0, 0);
            acc2[1][0] = __builtin_amdgcn_mfma_f32_16x16x32_bf16(aA1, b20, acc2[1][0], 0, 0, 0);
            acc2[1][1] = __builtin_amdgcn_mfma_f32_16x16x32_bf16(aA1, b21, acc2[1][1], 0, 0, 0);
        }
    }

    #pragma unroll
    for (int ag = 0; ag < 2; ++ag)
        #pragma unroll
        for (int cg = 0; cg < 2; ++cg)
            #pragma unroll
            for (int i = 0; i < 4; ++i)
                C1[(size_t)(r0 + rw + ag * 16 + quad * 4 + i) * 256
                   + c0 + cw + cg * 16 + l16] = f2bf(acc1[ag][cg][i]);

    if (!trans2) {
        #pragma unroll
        for (int ag = 0; ag < 2; ++ag)
            #pragma unroll
            for (int cg = 0; cg < 2; ++cg)
                #pragma unroll
                for (int i = 0; i < 4; ++i)
                    C2[(size_t)(r0 + rw + ag * 16 + quad * 4 + i) * 256
                       + c0 + cw + cg * 16 + l16] = f2bf(acc2[ag][cg][i]);
    } else {
        __syncthreads();
        #pragma unroll
        for (int ag = 0; ag < 2; ++ag)
            #pragma unroll
            for (int cg = 0; cg < 2; ++cg)
                #pragma unroll
                for (int i = 0; i < 4; ++i)
                    W2s[cw + cg * 16 + l16][rw + ag * 16 + quad * 4 + i] = f2bf(acc2[ag][cg][i]);
        __syncthreads();
        const int col = tid >> 2;
        const int seg = (tid & 3) * 16;
        #pragma unroll
        for (int j = 0; j < 2; ++j)
            *(uint4*)(C2 + (size_t)(c0 + col) * nrows + r0 + seg + j * 8) =
                *(const uint4*)&W2s[col][seg + j * 8];
    }
}

// ---------------- KF row stats only (Q stats inline in fused) ----------------
__global__ __launch_bounds__(256) void row_stats_kf(
    const ushort* __restrict__ KFb, float* __restrict__ km, float* __restrict__ kv)
{
    const int row  = blockIdx.x * 4 + (threadIdx.x >> 6);
    const int lane = threadIdx.x & 63;
    ushort4 u = *(const ushort4*)(KFb + (size_t)row * 256 + lane * 4);
    float a = bf2f(u.x), b = bf2f(u.y), c = bf2f(u.z), d = bf2f(u.w);
    float s  = a + b + c + d;
    float ss = a * a + b * b + c * c + d * d;
    #pragma unroll
    for (int off = 32; off > 0; off >>= 1) {
        s  += __shfl_down(s, off);
        ss += __shfl_down(ss, off);
    }
    if (lane == 0) {
        float m = s * (1.f / 256.f);
        km[row] = m;
        kv[row] = (ss - 256.f * m * m) * (1.f / 255.f);
    }
}

// ---------------- fused dual attention: NO-LDS main loop, direct L2 fragments ----
// K/V tiles have LDS-reuse of only 2 (each wave reads its tile exactly once) — not
// worth the stage+drain+barrier serialization that capped r13/r14 at ~190us. Each
// wave loads MFMA fragments straight from global (K/V are 1MB each -> L2-resident).
// Fragment row mapping bakes in the r13 'pr' permutation (global row = prinv(l16)),
// so all MFMA operands are bit-identical to r13. Zero barriers in the main loop:
// latency hides via TLP (784 blocks x 4 waves, no LDS cap) + multi-load scheduling.
template<int NHALF>
__global__ __launch_bounds__(256, 3) void fused_attn_st(
    const ushort* __restrict__ Qb,  const ushort* __restrict__ QFb,
    const ushort* __restrict__ Kb,  const ushort* __restrict__ KFb,
    const ushort* __restrict__ Vtb, const ushort* __restrict__ VFtb,
    const float* __restrict__ km_, const float* __restrict__ kv_,
    float* __restrict__ out, float* __restrict__ part, float* __restrict__ denp)
{
    __shared__ float combuf[(NHALF == 1) ? 8192 : 4];   // 32KB only in fallback path

    const int tid  = threadIdx.x;
    const int wv   = tid >> 6;
    const int lane = tid & 63;
    const int quad = lane >> 4;
    const int l16  = lane & 15;
    const int qsel = wv & 1;
    const int br   = wv >> 1;          // 0 = channel, 1 = spatial

    const int bid   = blockIdx.x;
    const int half  = (NHALF == 2) ? (bid & 1) : 0;
    const int qc    = (NHALF == 2) ? (bid >> 1) : bid;
    const int q0    = qc * 32;
    const int kbase = half * (MM / NHALF);
    const int NT    = (MM / NHALF) / 32;

    const ushort* qsrc = br ? QFb : Qb;
    bf16x8 aQ[8];
    {
        const ushort* qp = qsrc + (size_t)(q0 + qsel * 16 + l16) * DM + quad * 8;
        #pragma unroll
        for (int s = 0; s < 8; ++s) aQ[s] = *(const bf16x8*)(qp + s * 32);
    }

    float qmv = 0.f, qvv = 0.f;
    if (br) {
        float sum = 0.f, ss = 0.f;
        #pragma unroll
        for (int s = 0; s < 8; ++s)
            #pragma unroll
            for (int j = 0; j < 8; ++j) {
                float v = (float)aQ[s][j];
                sum += v; ss += v * v;
            }
        sum += __shfl_xor(sum, 16, 64); sum += __shfl_xor(sum, 32, 64);
        ss  += __shfl_xor(ss, 16, 64);  ss  += __shfl_xor(ss, 32, 64);
        qmv = sum * (1.f / 256.f);
        qvv = (ss - 256.f * qmv * qmv) * (1.f / 255.f);
    }

    // Direct-fragment base pointers. Global K row for the A-frag slot that r13 read
    // from LDS row l16 is prinv(l16) = (l16&3) + (l16>>2)*8 (and +4 for row 16+l16).
    const ushort* Ksel = br ? KFb : Kb;
    const ushort* Vsel = br ? VFtb : Vtb;
    const int rk0 = (l16 & 3) + (l16 >> 2) * 8;
    const ushort* kp0 = Ksel + (size_t)(kbase + rk0) * DM + quad * 8;
    const ushort* kp1 = kp0 + 4 * DM;
    const ushort* vp  = Vsel + (size_t)l16 * MM + kbase + quad * 8;

    floatx4 acc[16];
    #pragma unroll
    for (int t = 0; t < 16; ++t) acc[t] = (floatx4){0.f, 0.f, 0.f, 0.f};
    float den = 0.f;

    for (int ti = 0; ti < NT; ++ti) {
        floatx4 S0 = (floatx4){0.f, 0.f, 0.f, 0.f};
        floatx4 S1 = (floatx4){0.f, 0.f, 0.f, 0.f};
        #pragma unroll
        for (int s = 0; s < 8; ++s) {
            bf16x8 aK0 = *(const bf16x8*)(kp0 + s * 32);
            bf16x8 aK1 = *(const bf16x8*)(kp1 + s * 32);
            S0 = __builtin_amdgcn_mfma_f32_16x16x32_bf16(aK0, aQ[s], S0, 0, 0, 0);
            S1 = __builtin_amdgcn_mfma_f32_16x16x32_bf16(aK1, aQ[s], S1, 0, 0, 0);
        }

        const int kk = kbase + ti * 32;
        float pb[8];
        if (!br) {
            #pragma unroll
            for (int r = 0; r < 4; ++r) {
                pb[r]     = __expf(S0[r] * 0.0625f);
                pb[4 + r] = __expf(S1[r] * 0.0625f);
            }
        } else {
            floatx4 km0 = *(const floatx4*)(km_ + kk + 8 * quad);
            floatx4 km1 = *(const floatx4*)(km_ + kk + 8 * quad + 4);
            floatx4 kv0 = *(const floatx4*)(kv_ + kk + 8 * quad);
            floatx4 kv1 = *(const floatx4*)(kv_ + kk + 8 * quad + 4);
            #pragma unroll
            for (int r = 0; r < 4; ++r) {
                {
                    float mp  = qmv * km0[r];
                    float cov = (S0[r] - 256.f * mp) * (1.f / 255.f);
                    float num = (2.f * mp + 0.01f) * (2.f * cov + 0.03f);
                    float dn  = (qmv * qmv + km0[r] * km0[r] + 0.01f) * (qvv + kv0[r] + 0.03f);
                    pb[r] = __expf(num / (dn + 1e-8f));
                }
                {
                    float mp  = qmv * km1[r];
                    float cov = (S1[r] - 256.f * mp) * (1.f / 255.f);
                    float num = (2.f * mp + 0.01f) * (2.f * cov + 0.03f);
                    float dn  = (qmv * qmv + km1[r] * km1[r] + 0.01f) * (qvv + kv1[r] + 0.03f);
                    pb[4 + r] = __expf(num / (dn + 1e-8f));
                }
            }
        }
        union { ushort u[8]; bf16x8 v; } ap;
        #pragma unroll
        for (int j = 0; j < 8; ++j) {
            den += pb[j];
            ap.u[j] = f2bf(pb[j]);
        }

        #pragma unroll
        for (int t = 0; t < 16; ++t) {
            bf16x8 bV = *(const bf16x8*)(vp + (size_t)t * 16 * MM);
            acc[t] = __builtin_amdgcn_mfma_f32_16x16x32_bf16(ap.v, bV, acc[t], 0, 0, 0);
        }

        kp0 += 32 * DM;
        kp1 += 32 * DM;
        vp  += 32;
    }

    den += __shfl_xor(den, 16, 64);
    den += __shfl_xor(den, 32, 64);

    if (NHALF == 1) {
        float rdn[4];
        #pragma unroll
        for (int r = 0; r < 4; ++r)
            rdn[r] = 1.f / __shfl(den, quad * 4 + r, 64);

        __syncthreads();
        if (br) {
            #pragma unroll
            for (int t = 0; t < 16; ++t)
                #pragma unroll
                for (int r = 0; r < 4; ++r)
                    combuf[(qsel * 16 + quad * 4 + r) * 256 + t * 16 + l16] = acc[t][r] * rdn[r];
        }
        __syncthreads();
        if (!br) {
            #pragma unroll
            for (int t = 0; t < 16; ++t)
                #pragma unroll
                for (int r = 0; r < 4; ++r) {
                    int ql = qsel * 16 + quad * 4 + r;
                    out[(size_t)(q0 + ql) * DM + t * 16 + l16] =
                        acc[t][r] * rdn[r] + combuf[ql * 256 + t * 16 + l16];
                }
        }
    } else {
        float* Np = part + (size_t)(half * 2 + br) * ((size_t)NBQ * DM);
        #pragma unroll
        for (int t = 0; t < 16; ++t)
            #pragma unroll
            for (int r = 0; r < 4; ++r)
                Np[(size_t)(q0 + qsel * 16 + quad * 4 + r) * DM + t * 16 + l16] = acc[t][r];
        if (lane < 16)
            denp[(size_t)(half * 2 + br) * NBQ + q0 + qsel * 16 + lane] = den;
    }
}

// ---------------- combine the two MEM-halves (per-branch normalize, sum) ----------
__global__ __launch_bounds__(256) void combine_halves(
    const float* __restrict__ part, const float* __restrict__ denp,
    float* __restrict__ out)
{
    const size_t stride = (size_t)NBQ * 64;         // float4 units per section
    const float4* p4 = (const float4*)part;
    float4* o4 = (float4*)out;
    #pragma unroll
    for (int u = 0; u < 2; ++u) {
        size_t i = (size_t)blockIdx.x * 512 + (size_t)u * 256 + threadIdx.x;
        int q = (int)(i >> 6);
        float rc = 1.f / (denp[q] + denp[2 * NBQ + q]);
        float rs = 1.f / (denp[NBQ + q] + denp[3 * NBQ + q]);
        float4 c0 = p4[i];
        float4 s0 = p4[stride + i];
        float4 c1 = p4[2 * stride + i];
        float4 s1 = p4[3 * stride + i];
        float4 r;
        r.x = (c0.x + c1.x) * rc + (s0.x + s1.x) * rs;
        r.y = (c0.y + c1.y) * rc + (s0.y + s1.y) * rs;
        r.z = (c0.z + c1.z) * rc + (s0.z + s1.z) * rs;
        r.w = (c0.w + c1.w) * rc + (s0.w + s1.w) * rs;
        o4[i] = r;
    }
}

extern "C" void kernel_launch(void* const* d_in, const int* in_sizes, int n_in,
                              void* d_out, int out_size, void* d_ws, size_t ws_size,
                              hipStream_t stream)
{
    const float* x      = (const float*)d_in[0];
    const float* ch_mem = (const float*)d_in[1];
    const float* ch_wq  = (const float*)d_in[2];
    const float* ch_wk  = (const float*)d_in[3];
    const float* ch_wv  = (const float*)d_in[4];
    const float* sp_mem = (const float*)d_in[5];
    const float* sp_wq  = (const float*)d_in[6];
    const float* sp_wk  = (const float*)d_in[7];
    const float* sp_wv  = (const float*)d_in[8];
    float* out = (float*)d_out;

    ushort* Qb   = (ushort*)d_ws;                 // [12544][256]
    ushort* QFb  = Qb   + (size_t)NBQ * DM;
    ushort* Kb   = QFb  + (size_t)NBQ * DM;       // [2048][256]
    ushort* KFb  = Kb   + (size_t)MM * DM;
    ushort* Vtb  = KFb  + (size_t)MM * DM;        // [256][2048] transposed
    ushort* VFtb = Vtb  + (size_t)MM * DM;
    float*  km   = (float*)(VFtb + (size_t)MM * DM);
    float*  kv   = km + MM;
    float*  part = kv + MM;                       // [4][12544][256] f32 partial numerators
    float*  denp = part + (size_t)4 * NBQ * DM;   // [4][12544] partial denominators

    const size_t base_b = (2 * (size_t)NBQ * DM + 4 * (size_t)MM * DM) * sizeof(ushort)
                        + 2 * (size_t)MM * sizeof(float);
    const size_t need   = base_b + ((size_t)4 * NBQ * DM + 4 * NBQ) * sizeof(float);
    const bool split = ws_size >= need;

    dim3 blk(256);
    gemm_proj_all<<<dim3(1040), blk, 0, stream>>>(
        x, ch_mem, ch_wq, ch_wk, ch_wv, sp_mem, sp_wq, sp_wk, sp_wv,
        Qb, QFb, Kb, KFb, Vtb, VFtb);
    row_stats_kf<<<dim3(MM / 4), blk, 0, stream>>>(KFb, km, kv);
    if (split) {
        fused_attn_st<2><<<dim3(2 * NBQ / 32), blk, 0, stream>>>(
            Qb, QFb, Kb, KFb, Vtb, VFtb, km, kv, out, part, denp);
        combine_halves<<<dim3(NBQ * DM / 4 / 512), blk, 0, stream>>>(part, denp, out);
    } else {
        fused_attn_st<1><<<dim3(NBQ / 32), blk, 0, stream>>>(
            Qb, QFb, Kb, KFb, Vtb, VFtb, km, kv, out, part, denp);
    }
}

// Round 3
// 258.167 us; speedup vs baseline: 2.3383x; 2.3383x over previous
//
#include <hip/hip_runtime.h>

#define NBQ 12544
#define DM  256
#define MM  2048

typedef __attribute__((ext_vector_type(8)))  __bf16 bf16x8;
typedef __attribute__((ext_vector_type(4)))  float  floatx4;

__device__ __forceinline__ ushort f2bf(float x) {
    unsigned u = __float_as_uint(x);
    u += 0x7fffu + ((u >> 16) & 1u);   // RNE
    return (ushort)(u >> 16);
}
__device__ __forceinline__ float bf2f(ushort h) {
    return __uint_as_float(((unsigned)h) << 16);
}

// async global->LDS, 16B per lane; dest = wave-uniform base + lane*16
__device__ __forceinline__ void glds16(const ushort* g, ushort* l) {
    __builtin_amdgcn_global_load_lds(
        (const __attribute__((address_space(1))) unsigned int*)g,
        (__attribute__((address_space(3))) unsigned int*)l, 16, 0, 0);
}

// ---------- projections, weight-pairs folded; 2-phase reg prefetch ----------
__global__ __launch_bounds__(256) void gemm_proj_all(
    const float* __restrict__ x,      const float* __restrict__ ch_mem,
    const float* __restrict__ ch_wq,  const float* __restrict__ ch_wk,
    const float* __restrict__ ch_wv,  const float* __restrict__ sp_mem,
    const float* __restrict__ sp_wq,  const float* __restrict__ sp_wk,
    const float* __restrict__ sp_wv,
    ushort* __restrict__ Qb,  ushort* __restrict__ QFb,
    ushort* __restrict__ Kb,  ushort* __restrict__ KFb,
    ushort* __restrict__ Vtb, ushort* __restrict__ VFtb)
{
    __shared__ ushort As[64][72];
    __shared__ ushort W1s[64][72];
    __shared__ ushort W2s[64][72];

    int bid = blockIdx.x;
    const float* A; const float* W1; const float* W2;
    ushort* C1; ushort* C2; int nrows, trans2;
    if (bid < 784) {
        A = x; W1 = ch_wq; W2 = sp_wq; C1 = Qb; C2 = QFb; nrows = NBQ; trans2 = 0;
    } else if (bid < 912) {
        A = ch_mem; W1 = ch_wk; W2 = ch_wv; C1 = Kb; C2 = Vtb;
        nrows = MM; trans2 = 1; bid -= 784;
    } else {
        A = sp_mem; W1 = sp_wk; W2 = sp_wv; C1 = KFb; C2 = VFtb;
        nrows = MM; trans2 = 1; bid -= 912;
    }
    const int r0 = (bid >> 2) * 64;
    const int c0 = (bid & 3) * 64;

    const int tid  = threadIdx.x;
    const int wv   = tid >> 6;
    const int lane = tid & 63;
    const int quad = lane >> 4;
    const int l16  = lane & 15;
    const int rw = (wv & 1) * 32;
    const int cw = (wv >> 1) * 32;

    floatx4 acc1[2][2], acc2[2][2];
    #pragma unroll
    for (int i = 0; i < 2; ++i)
        #pragma unroll
        for (int j = 0; j < 2; ++j) {
            acc1[i][j] = (floatx4){0.f, 0.f, 0.f, 0.f};
            acc2[i][j] = (floatx4){0.f, 0.f, 0.f, 0.f};
        }

    float4 a4[4], w14[4], w24[4];
    #pragma unroll
    for (int it = 0; it < 4; ++it) {
        int idx = tid + it * 256;
        int r = idx >> 4, c4 = (idx & 15) * 4;
        a4[it]  = *(const float4*)(A  + (size_t)(r0 + r) * 256 + c4);
        w14[it] = *(const float4*)(W1 + (size_t)(c0 + r) * 256 + c4);
        w24[it] = *(const float4*)(W2 + (size_t)(c0 + r) * 256 + c4);
    }

    for (int d0 = 0; d0 < 256; d0 += 64) {
        __syncthreads();
        #pragma unroll
        for (int it = 0; it < 4; ++it) {
            int idx = tid + it * 256;
            int r = idx >> 4, c4 = (idx & 15) * 4;
            ushort4 ab, w1b, w2b;
            ab.x = f2bf(a4[it].x);  ab.y = f2bf(a4[it].y);  ab.z = f2bf(a4[it].z);  ab.w = f2bf(a4[it].w);
            w1b.x = f2bf(w14[it].x); w1b.y = f2bf(w14[it].y); w1b.z = f2bf(w14[it].z); w1b.w = f2bf(w14[it].w);
            w2b.x = f2bf(w24[it].x); w2b.y = f2bf(w24[it].y); w2b.z = f2bf(w24[it].z); w2b.w = f2bf(w24[it].w);
            *(ushort4*)&As[r][c4]  = ab;
            *(ushort4*)&W1s[r][c4] = w1b;
            *(ushort4*)&W2s[r][c4] = w2b;
        }
        if (d0 + 64 < 256) {
            #pragma unroll
            for (int it = 0; it < 4; ++it) {
                int idx = tid + it * 256;
                int r = idx >> 4, c4 = (idx & 15) * 4;
                a4[it]  = *(const float4*)(A  + (size_t)(r0 + r) * 256 + d0 + 64 + c4);
                w14[it] = *(const float4*)(W1 + (size_t)(c0 + r) * 256 + d0 + 64 + c4);
                w24[it] = *(const float4*)(W2 + (size_t)(c0 + r) * 256 + d0 + 64 + c4);
            }
        }
        __syncthreads();
        #pragma unroll
        for (int kk = 0; kk < 64; kk += 32) {
            bf16x8 aA0 = *(const bf16x8*)&As[rw + l16][kk + quad * 8];
            bf16x8 aA1 = *(const bf16x8*)&As[rw + 16 + l16][kk + quad * 8];
            bf16x8 b10 = *(const bf16x8*)&W1s[cw + l16][kk + quad * 8];
            bf16x8 b11 = *(const bf16x8*)&W1s[cw + 16 + l16][kk + quad * 8];
            bf16x8 b20 = *(const bf16x8*)&W2s[cw + l16][kk + quad * 8];
            bf16x8 b21 = *(const bf16x8*)&W2s[cw + 16 + l16][kk + quad * 8];
            acc1[0][0] = __builtin_amdgcn_mfma_f32_16x16x32_bf16(aA0, b10, acc1[0][0], 0, 0, 0);
            acc1[0][1] = __builtin_amdgcn_mfma_f32_16x16x32_bf16(aA0, b11, acc1[0][1], 0, 0, 0);
            acc1[1][0] = __builtin_amdgcn_mfma_f32_16x16x32_bf16(aA1, b10, acc1[1][0], 0, 0, 0);
            acc1[1][1] = __builtin_amdgcn_mfma_f32_16x16x32_bf16(aA1, b11, acc1[1][1], 0, 0, 0);
            acc2[0][0] = __builtin_amdgcn_mfma_f32_16x16x32_bf16(aA0, b20, acc2[0][0], 0, 0, 0);
            acc2[0][1] = __builtin_amdgcn_mfma_f32_16x16x32_bf16(aA0, b21, acc2[0][1], 0, 0, 0);
            acc2[1][0] = __builtin_amdgcn_mfma_f32_16x16x32_bf16(aA1, b20, acc2[1][0], 0, 0, 0);
            acc2[1][1] = __builtin_amdgcn_mfma_f32_16x16x32_bf16(aA1, b21, acc2[1][1], 0, 0, 0);
        }
    }

    #pragma unroll
    for (int ag = 0; ag < 2; ++ag)
        #pragma unroll
        for (int cg = 0; cg < 2; ++cg)
            #pragma unroll
            for (int i = 0; i < 4; ++i)
                C1[(size_t)(r0 + rw + ag * 16 + quad * 4 + i) * 256
                   + c0 + cw + cg * 16 + l16] = f2bf(acc1[ag][cg][i]);

    if (!trans2) {
        #pragma unroll
        for (int ag = 0; ag < 2; ++ag)
            #pragma unroll
            for (int cg = 0; cg < 2; ++cg)
                #pragma unroll
                for (int i = 0; i < 4; ++i)
                    C2[(size_t)(r0 + rw + ag * 16 + quad * 4 + i) * 256
                       + c0 + cw + cg * 16 + l16] = f2bf(acc2[ag][cg][i]);
    } else {
        __syncthreads();
        #pragma unroll
        for (int ag = 0; ag < 2; ++ag)
            #pragma unroll
            for (int cg = 0; cg < 2; ++cg)
                #pragma unroll
                for (int i = 0; i < 4; ++i)
                    W2s[cw + cg * 16 + l16][rw + ag * 16 + quad * 4 + i] = f2bf(acc2[ag][cg][i]);
        __syncthreads();
        const int col = tid >> 2;
        const int seg = (tid & 3) * 16;
        #pragma unroll
        for (int j = 0; j < 2; ++j)
            *(uint4*)(C2 + (size_t)(c0 + col) * nrows + r0 + seg + j * 8) =
                *(const uint4*)&W2s[col][seg + j * 8];
    }
}

// ---------------- KF row stats only (Q stats inline in fused) ----------------
__global__ __launch_bounds__(256) void row_stats_kf(
    const ushort* __restrict__ KFb, float* __restrict__ km, float* __restrict__ kv)
{
    const int row  = blockIdx.x * 4 + (threadIdx.x >> 6);
    const int lane = threadIdx.x & 63;
    ushort4 u = *(const ushort4*)(KFb + (size_t)row * 256 + lane * 4);
    float a = bf2f(u.x), b = bf2f(u.y), c = bf2f(u.z), d = bf2f(u.w);
    float s  = a + b + c + d;
    float ss = a * a + b * b + c * c + d * d;
    #pragma unroll
    for (int off = 32; off > 0; off >>= 1) {
        s  += __shfl_down(s, off);
        ss += __shfl_down(ss, off);
    }
    if (lane == 0) {
        float m = s * (1.f / 256.f);
        km[row] = m;
        kv[row] = (ss - 256.f * m * m) * (1.f / 255.f);
    }
}

// ---------------- fused attention: one branch/block, W=32 q/wave, 2-phase dbuf ----
// Fixes r1's serial schedule: glds for tile ti+1 issued BEFORE computing tile ti;
// the vmcnt(0) inside the single end-of-tile __syncthreads then waits on loads that
// had the whole compute phase to land (issue-early/wait-late, T3 minimum 2-phase).
// One branch per block halves per-tile LDS to 32KB -> 64KB dbuf -> 2 blocks/CU.
// Each wave serves 2 query-groups (32 q), so every K/V fragment read feeds 2 MFMAs
// (LDS-read floor halves: ~150K -> ~75K cyc/CU). Swizzle/permutation identical to r1
// (verified): K LDS row R = global row prinv(R), chunk c holds src chunk c^(R&7);
// Vt row R chunk c holds src chunk c^(R&3).
#define STAGE_TILE(b, ti)                                                     \
    {                                                                         \
        const ushort* kp_ = kp0 + (size_t)(ti) * 32 * DM;                     \
        const ushort* vp_ = vp0 + (ti) * 32;                                  \
        ushort* dst_ = SMu + (b) * 16384;                                     \
        _Pragma("unroll")                                                     \
        for (int p = 0; p < 4; ++p) {                                         \
            int db = (wv * 4 + p) * 512;                                      \
            glds16(kp_ + offK[p], dst_ + db);                                 \
            glds16(vp_ + offV[p], dst_ + 8192 + db);                          \
        }                                                                     \
    }

template<int NHALF>
__global__ __launch_bounds__(256, 2) void fused_attn_1br(
    const ushort* __restrict__ Qb,  const ushort* __restrict__ QFb,
    const ushort* __restrict__ Kb,  const ushort* __restrict__ KFb,
    const ushort* __restrict__ Vtb, const ushort* __restrict__ VFtb,
    const float* __restrict__ km_, const float* __restrict__ kv_,
    float* __restrict__ part, float* __restrict__ denp)
{
    __shared__ ushort SMu[32768];   // 64KB: buf{0,1} x {K 16KB, Vt 16KB}

    const int tid  = threadIdx.x;
    const int wv   = tid >> 6;
    const int lane = tid & 63;
    const int quad = lane >> 4;
    const int l16  = lane & 15;

    const int NQC = NBQ / 128;             // 98
    const int per_br = NQC * NHALF;
    int bid = blockIdx.x;
    const int br  = (bid < per_br) ? 1 : 0;     // sp blocks first (heavier)
    int rem = br ? bid : bid - per_br;
    const int half = rem / NQC;
    const int qc   = rem - half * NQC;
    const int q0   = qc * 128;
    const int kbase = half * (MM / NHALF);
    const int NT   = (MM / NHALF) / 32;

    const ushort* qsrc = br ? QFb : Qb;
    const ushort* Ksel = br ? KFb : Kb;
    const ushort* Vsel = br ? VFtb : Vtb;

    // Q fragments for both 16-query groups of this wave
    bf16x8 aQ0[8], aQ1[8];
    {
        const ushort* qp = qsrc + (size_t)(q0 + wv * 32 + l16) * DM + quad * 8;
        #pragma unroll
        for (int s = 0; s < 8; ++s) {
            aQ0[s] = *(const bf16x8*)(qp + s * 32);
            aQ1[s] = *(const bf16x8*)(qp + 16 * DM + s * 32);
        }
    }

    float qmv0 = 0.f, qvv0 = 0.f, qmv1 = 0.f, qvv1 = 0.f;
    if (br) {
        float s0 = 0.f, ss0 = 0.f, s1 = 0.f, ss1 = 0.f;
        #pragma unroll
        for (int s = 0; s < 8; ++s)
            #pragma unroll
            for (int j = 0; j < 8; ++j) {
                float v0 = (float)aQ0[s][j], v1 = (float)aQ1[s][j];
                s0 += v0; ss0 += v0 * v0; s1 += v1; ss1 += v1 * v1;
            }
        s0  += __shfl_xor(s0, 16, 64);  s0  += __shfl_xor(s0, 32, 64);
        ss0 += __shfl_xor(ss0, 16, 64); ss0 += __shfl_xor(ss0, 32, 64);
        s1  += __shfl_xor(s1, 16, 64);  s1  += __shfl_xor(s1, 32, 64);
        ss1 += __shfl_xor(ss1, 16, 64); ss1 += __shfl_xor(ss1, 32, 64);
        qmv0 = s0 * (1.f / 256.f);
        qvv0 = (ss0 - 256.f * qmv0 * qmv0) * (1.f / 255.f);
        qmv1 = s1 * (1.f / 256.f);
        qvv1 = (ss1 - 256.f * qmv1 * qmv1) * (1.f / 255.f);
    }

    int offK[4], offV[4];
    #pragma unroll
    for (int p = 0; p < 4; ++p) {
        int j  = wv * 4 + p;
        int Rk = 2 * j + (lane >> 5);
        int rk = (Rk & 3) + ((Rk >> 4) & 1) * 4 + ((Rk >> 2) & 3) * 8;   // prinv
        int ck = (lane & 31) ^ (Rk & 7);
        offK[p] = rk * DM + ck * 8;
        int Rv = 16 * j + (lane >> 2);
        int cv = (lane & 3) ^ (Rv & 3);
        offV[p] = Rv * MM + cv * 8;
    }

    const ushort* kp0 = Ksel + (size_t)kbase * DM;
    const ushort* vp0 = Vsel + kbase;

    floatx4 acc0[16], acc1[16];
    #pragma unroll
    for (int t = 0; t < 16; ++t) {
        acc0[t] = (floatx4){0.f, 0.f, 0.f, 0.f};
        acc1[t] = (floatx4){0.f, 0.f, 0.f, 0.f};
    }
    float den0 = 0.f, den1 = 0.f;
    const int ksw  = l16 & 7;
    const int vswo = (quad ^ (l16 & 3)) * 8;

    STAGE_TILE(0, 0);
    __syncthreads();

    int buf = 0;
    for (int ti = 0; ti < NT; ++ti) {
        if (ti + 1 < NT) STAGE_TILE(buf ^ 1, ti + 1);   // issue-early, wait-late

        const ushort* Ks = SMu + buf * 16384;
        const ushort* Vs = Ks + 8192;

        floatx4 S00 = (floatx4){0.f, 0.f, 0.f, 0.f};
        floatx4 S10 = (floatx4){0.f, 0.f, 0.f, 0.f};
        floatx4 S01 = (floatx4){0.f, 0.f, 0.f, 0.f};
        floatx4 S11 = (floatx4){0.f, 0.f, 0.f, 0.f};
        #pragma unroll
        for (int s = 0; s < 8; ++s) {
            int off = ((s * 4 + quad) ^ ksw) * 8;
            bf16x8 aK0 = *(const bf16x8*)(Ks + l16 * DM + off);
            bf16x8 aK1 = *(const bf16x8*)(Ks + 4096 + l16 * DM + off);
            S00 = __builtin_amdgcn_mfma_f32_16x16x32_bf16(aK0, aQ0[s], S00, 0, 0, 0);
            S10 = __builtin_amdgcn_mfma_f32_16x16x32_bf16(aK1, aQ0[s], S10, 0, 0, 0);
            S01 = __builtin_amdgcn_mfma_f32_16x16x32_bf16(aK0, aQ1[s], S01, 0, 0, 0);
            S11 = __builtin_amdgcn_mfma_f32_16x16x32_bf16(aK1, aQ1[s], S11, 0, 0, 0);
        }

        const int kk = kbase + ti * 32;
        float p0[8], p1[8];
        if (!br) {
            #pragma unroll
            for (int r = 0; r < 4; ++r) {
                p0[r]     = __expf(S00[r] * 0.0625f);
                p0[4 + r] = __expf(S10[r] * 0.0625f);
                p1[r]     = __expf(S01[r] * 0.0625f);
                p1[4 + r] = __expf(S11[r] * 0.0625f);
            }
        } else {
            floatx4 km0 = *(const floatx4*)(km_ + kk + 8 * quad);
            floatx4 km1 = *(const floatx4*)(km_ + kk + 8 * quad + 4);
            floatx4 kv0 = *(const floatx4*)(kv_ + kk + 8 * quad);
            floatx4 kv1 = *(const floatx4*)(kv_ + kk + 8 * quad + 4);
            #pragma unroll
            for (int r = 0; r < 4; ++r) {
                {
                    float mp  = qmv0 * km0[r];
                    float cov = (S00[r] - 256.f * mp) * (1.f / 255.f);
                    float num = (2.f * mp + 0.01f) * (2.f * cov + 0.03f);
                    float dn  = (qmv0 * qmv0 + km0[r] * km0[r] + 0.01f) * (qvv0 + kv0[r] + 0.03f);
                    p0[r] = __expf(num / (dn + 1e-8f));
                }
                {
                    float mp  = qmv0 * km1[r];
                    float cov = (S10[r] - 256.f * mp) * (1.f / 255.f);
                    float num = (2.f * mp + 0.01f) * (2.f * cov + 0.03f);
                    float dn  = (qmv0 * qmv0 + km1[r] * km1[r] + 0.01f) * (qvv0 + kv1[r] + 0.03f);
                    p0[4 + r] = __expf(num / (dn + 1e-8f));
                }
                {
                    float mp  = qmv1 * km0[r];
                    float cov = (S01[r] - 256.f * mp) * (1.f / 255.f);
                    float num = (2.f * mp + 0.01f) * (2.f * cov + 0.03f);
                    float dn  = (qmv1 * qmv1 + km0[r] * km0[r] + 0.01f) * (qvv1 + kv0[r] + 0.03f);
                    p1[r] = __expf(num / (dn + 1e-8f));
                }
                {
                    float mp  = qmv1 * km1[r];
                    float cov = (S11[r] - 256.f * mp) * (1.f / 255.f);
                    float num = (2.f * mp + 0.01f) * (2.f * cov + 0.03f);
                    float dn  = (qmv1 * qmv1 + km1[r] * km1[r] + 0.01f) * (qvv1 + kv1[r] + 0.03f);
                    p1[4 + r] = __expf(num / (dn + 1e-8f));
                }
            }
        }
        union { ushort u[8]; bf16x8 v; } ap0, ap1;
        #pragma unroll
        for (int j = 0; j < 8; ++j) {
            den0 += p0[j]; ap0.u[j] = f2bf(p0[j]);
            den1 += p1[j]; ap1.u[j] = f2bf(p1[j]);
        }

        #pragma unroll
        for (int t = 0; t < 16; ++t) {
            bf16x8 bV = *(const bf16x8*)(Vs + (t * 16 + l16) * 32 + vswo);
            acc0[t] = __builtin_amdgcn_mfma_f32_16x16x32_bf16(ap0.v, bV, acc0[t], 0, 0, 0);
            acc1[t] = __builtin_amdgcn_mfma_f32_16x16x32_bf16(ap1.v, bV, acc1[t], 0, 0, 0);
        }

        __syncthreads();     // drains vmcnt(0): prefetch had full compute phase to land
        buf ^= 1;
    }

    den0 += __shfl_xor(den0, 16, 64); den0 += __shfl_xor(den0, 32, 64);
    den1 += __shfl_xor(den1, 16, 64); den1 += __shfl_xor(den1, 32, 64);

    const int sec = br * NHALF + half;
    float* Np = part + (size_t)sec * ((size_t)NBQ * DM);
    #pragma unroll
    for (int t = 0; t < 16; ++t)
        #pragma unroll
        for (int r = 0; r < 4; ++r) {
            int row = q0 + wv * 32 + quad * 4 + r;
            Np[(size_t)row * DM + t * 16 + l16]        = acc0[t][r];
            Np[(size_t)(row + 16) * DM + t * 16 + l16] = acc1[t][r];
        }
    if (lane < 16) {
        denp[(size_t)sec * NBQ + q0 + wv * 32 + lane]      = den0;
        denp[(size_t)sec * NBQ + q0 + wv * 32 + 16 + lane] = den1;
    }
}

// ---------------- fallback (r1-proven two-branch serial kernel, direct out) -------
__global__ __launch_bounds__(256, 2) void fused_attn_fb(
    const ushort* __restrict__ Qb,  const ushort* __restrict__ QFb,
    const ushort* __restrict__ Kb,  const ushort* __restrict__ KFb,
    const ushort* __restrict__ Vtb, const ushort* __restrict__ VFtb,
    const float* __restrict__ km_, const float* __restrict__ kv_,
    float* __restrict__ out)
{
    __shared__ ushort SMu[32768];
    float* combuf = (float*)SMu;

    const int tid  = threadIdx.x;
    const int wv   = tid >> 6;
    const int lane = tid & 63;
    const int quad = lane >> 4;
    const int l16  = lane & 15;
    const int qsel = wv & 1;
    const int br   = wv >> 1;
    const int q0   = blockIdx.x * 32;

    const ushort* qsrc = br ? QFb : Qb;
    bf16x8 aQ[8];
    {
        const ushort* qp = qsrc + (size_t)(q0 + qsel * 16 + l16) * DM + quad * 8;
        #pragma unroll
        for (int s = 0; s < 8; ++s) aQ[s] = *(const bf16x8*)(qp + s * 32);
    }

    float qmv = 0.f, qvv = 0.f;
    if (br) {
        float sum = 0.f, ss = 0.f;
        #pragma unroll
        for (int s = 0; s < 8; ++s)
            #pragma unroll
            for (int j = 0; j < 8; ++j) {
                float v = (float)aQ[s][j];
                sum += v; ss += v * v;
            }
        sum += __shfl_xor(sum, 16, 64); sum += __shfl_xor(sum, 32, 64);
        ss  += __shfl_xor(ss, 16, 64);  ss  += __shfl_xor(ss, 32, 64);
        qmv = sum * (1.f / 256.f);
        qvv = (ss - 256.f * qmv * qmv) * (1.f / 255.f);
    }

    int offK[4], offV[4];
    #pragma unroll
    for (int p = 0; p < 4; ++p) {
        int j  = wv * 4 + p;
        int Rk = 2 * j + (lane >> 5);
        int rk = (Rk & 3) + ((Rk >> 4) & 1) * 4 + ((Rk >> 2) & 3) * 8;
        int ck = (lane & 31) ^ (Rk & 7);
        offK[p] = rk * DM + ck * 8;
        int Rv = 16 * j + (lane >> 2);
        int cv = (lane & 3) ^ (Rv & 3);
        offV[p] = Rv * MM + cv * 8;
    }

    const ushort* kp  = Kb;
    const ushort* kfp = KFb;
    const ushort* vp  = Vtb;
    const ushort* vfp = VFtb;

    floatx4 acc[16];
    #pragma unroll
    for (int t = 0; t < 16; ++t) acc[t] = (floatx4){0.f, 0.f, 0.f, 0.f};
    float den = 0.f;

    const int ksw  = l16 & 7;
    const int vswo = (quad ^ (l16 & 3)) * 8;

    for (int kt = 0; kt < MM; kt += 32) {
        __syncthreads();
        #pragma unroll
        for (int p = 0; p < 4; ++p) {
            int db = (wv * 4 + p) * 512;
            glds16(kp  + offK[p], SMu + db);
            glds16(kfp + offK[p], SMu + 4096 + db);
            glds16(vp  + offV[p], SMu + 16384 + db);
            glds16(vfp + offV[p], SMu + 24576 + db);
        }
        kp += 32 * DM; kfp += 32 * DM; vp += 32; vfp += 32;
        __syncthreads();

        const ushort* Ks = SMu + (br ? 4096 : 0);
        floatx4 S0 = (floatx4){0.f, 0.f, 0.f, 0.f};
        floatx4 S1 = (floatx4){0.f, 0.f, 0.f, 0.f};
        #pragma unroll
        for (int s = 0; s < 8; ++s) {
            int off = ((s * 4 + quad) ^ ksw) * 8;
            bf16x8 aK0 = *(const bf16x8*)(Ks + l16 * DM + off);
            bf16x8 aK1 = *(const bf16x8*)(Ks + 2048 + l16 * DM + off);
            S0 = __builtin_amdgcn_mfma_f32_16x16x32_bf16(aK0, aQ[s], S0, 0, 0, 0);
            S1 = __builtin_amdgcn_mfma_f32_16x16x32_bf16(aK1, aQ[s], S1, 0, 0, 0);
        }

        float pb[8];
        if (!br) {
            #pragma unroll
            for (int r = 0; r < 4; ++r) {
                pb[r]     = __expf(S0[r] * 0.0625f);
                pb[4 + r] = __expf(S1[r] * 0.0625f);
            }
        } else {
            floatx4 km0 = *(const floatx4*)(km_ + kt + 8 * quad);
            floatx4 km1 = *(const floatx4*)(km_ + kt + 8 * quad + 4);
            floatx4 kv0 = *(const floatx4*)(kv_ + kt + 8 * quad);
            floatx4 kv1 = *(const floatx4*)(kv_ + kt + 8 * quad + 4);
            #pragma unroll
            for (int r = 0; r < 4; ++r) {
                {
                    float mp  = qmv * km0[r];
                    float cov = (S0[r] - 256.f * mp) * (1.f / 255.f);
                    float num = (2.f * mp + 0.01f) * (2.f * cov + 0.03f);
                    float dn  = (qmv * qmv + km0[r] * km0[r] + 0.01f) * (qvv + kv0[r] + 0.03f);
                    pb[r] = __expf(num / (dn + 1e-8f));
                }
                {
                    float mp  = qmv * km1[r];
                    float cov = (S1[r] - 256.f * mp) * (1.f / 255.f);
                    float num = (2.f * mp + 0.01f) * (2.f * cov + 0.03f);
                    float dn  = (qmv * qmv + km1[r] * km1[r] + 0.01f) * (qvv + kv1[r] + 0.03f);
                    pb[4 + r] = __expf(num / (dn + 1e-8f));
                }
            }
        }
        union { ushort u[8]; bf16x8 v; } ap;
        #pragma unroll
        for (int j = 0; j < 8; ++j) {
            den += pb[j];
            ap.u[j] = f2bf(pb[j]);
        }

        const ushort* Vs = SMu + (br ? 24576 : 16384);
        #pragma unroll
        for (int t = 0; t < 16; ++t) {
            bf16x8 bV = *(const bf16x8*)(Vs + (t * 16 + l16) * 32 + vswo);
            acc[t] = __builtin_amdgcn_mfma_f32_16x16x32_bf16(ap.v, bV, acc[t], 0, 0, 0);
        }
    }

    den += __shfl_xor(den, 16, 64);
    den += __shfl_xor(den, 32, 64);
    float rdn[4];
    #pragma unroll
    for (int r = 0; r < 4; ++r)
        rdn[r] = 1.f / __shfl(den, quad * 4 + r, 64);

    __syncthreads();
    if (br) {
        #pragma unroll
        for (int t = 0; t < 16; ++t)
            #pragma unroll
            for (int r = 0; r < 4; ++r)
                combuf[(qsel * 16 + quad * 4 + r) * 256 + t * 16 + l16] = acc[t][r] * rdn[r];
    }
    __syncthreads();
    if (!br) {
        #pragma unroll
        for (int t = 0; t < 16; ++t)
            #pragma unroll
            for (int r = 0; r < 4; ++r) {
                int ql = qsel * 16 + quad * 4 + r;
                out[(size_t)(q0 + ql) * DM + t * 16 + l16] =
                    acc[t][r] * rdn[r] + combuf[ql * 256 + t * 16 + l16];
            }
    }
}

// ---------------- combine the MEM-quarters (per-branch normalize, sum) ----------
template<int NH>
__global__ __launch_bounds__(256) void combine_halves(
    const float* __restrict__ part, const float* __restrict__ denp,
    float* __restrict__ out)
{
    const size_t stride = (size_t)NBQ * 64;         // float4 units per section
    const float4* p4 = (const float4*)part;
    float4* o4 = (float4*)out;
    #pragma unroll
    for (int u = 0; u < 2; ++u) {
        size_t i = (size_t)blockIdx.x * 512 + (size_t)u * 256 + threadIdx.x;
        int q = (int)(i >> 6);
        float dc = 0.f, ds = 0.f;
        #pragma unroll
        for (int h = 0; h < NH; ++h) {
            dc += denp[(size_t)h * NBQ + q];
            ds += denp[(size_t)(NH + h) * NBQ + q];
        }
        float rc = 1.f / dc, rs = 1.f / ds;
        float4 nc = {0.f, 0.f, 0.f, 0.f}, ns = {0.f, 0.f, 0.f, 0.f};
        #pragma unroll
        for (int h = 0; h < NH; ++h) {
            float4 c = p4[(size_t)h * stride + i];
            float4 s = p4[(size_t)(NH + h) * stride + i];
            nc.x += c.x; nc.y += c.y; nc.z += c.z; nc.w += c.w;
            ns.x += s.x; ns.y += s.y; ns.z += s.z; ns.w += s.w;
        }
        float4 r;
        r.x = nc.x * rc + ns.x * rs;
        r.y = nc.y * rc + ns.y * rs;
        r.z = nc.z * rc + ns.z * rs;
        r.w = nc.w * rc + ns.w * rs;
        o4[i] = r;
    }
}

extern "C" void kernel_launch(void* const* d_in, const int* in_sizes, int n_in,
                              void* d_out, int out_size, void* d_ws, size_t ws_size,
                              hipStream_t stream)
{
    const float* x      = (const float*)d_in[0];
    const float* ch_mem = (const float*)d_in[1];
    const float* ch_wq  = (const float*)d_in[2];
    const float* ch_wk  = (const float*)d_in[3];
    const float* ch_wv  = (const float*)d_in[4];
    const float* sp_mem = (const float*)d_in[5];
    const float* sp_wq  = (const float*)d_in[6];
    const float* sp_wk  = (const float*)d_in[7];
    const float* sp_wv  = (const float*)d_in[8];
    float* out = (float*)d_out;

    ushort* Qb   = (ushort*)d_ws;                 // [12544][256]
    ushort* QFb  = Qb   + (size_t)NBQ * DM;
    ushort* Kb   = QFb  + (size_t)NBQ * DM;       // [2048][256]
    ushort* KFb  = Kb   + (size_t)MM * DM;
    ushort* Vtb  = KFb  + (size_t)MM * DM;        // [256][2048] transposed
    ushort* VFtb = Vtb  + (size_t)MM * DM;
    float*  km   = (float*)(VFtb + (size_t)MM * DM);
    float*  kv   = km + MM;
    float*  denp = kv + MM;                       // up to 8 sections x [12544]
    float*  part = denp + (size_t)8 * NBQ;        // up to 8 x [12544][256] f32

    const size_t base_b = (size_t)((char*)part - (char*)d_ws);
    const size_t need4  = base_b + (size_t)8 * NBQ * DM * sizeof(float);
    const size_t need2  = base_b + (size_t)4 * NBQ * DM * sizeof(float);

    dim3 blk(256);
    gemm_proj_all<<<dim3(1040), blk, 0, stream>>>(
        x, ch_mem, ch_wq, ch_wk, ch_wv, sp_mem, sp_wq, sp_wk, sp_wv,
        Qb, QFb, Kb, KFb, Vtb, VFtb);
    row_stats_kf<<<dim3(MM / 4), blk, 0, stream>>>(KFb, km, kv);
    if (ws_size >= need4) {
        fused_attn_1br<4><<<dim3(2 * (NBQ / 128) * 4), blk, 0, stream>>>(
            Qb, QFb, Kb, KFb, Vtb, VFtb, km, kv, part, denp);
        combine_halves<4><<<dim3(NBQ * DM / 4 / 512), blk, 0, stream>>>(part, denp, out);
    } else if (ws_size >= need2) {
        fused_attn_1br<2><<<dim3(2 * (NBQ / 128) * 2), blk, 0, stream>>>(
            Qb, QFb, Kb, KFb, Vtb, VFtb, km, kv, part, denp);
        combine_halves<2><<<dim3(NBQ * DM / 4 / 512), blk, 0, stream>>>(part, denp, out);
    } else {
        fused_attn_fb<<<dim3(NBQ / 32), blk, 0, stream>>>(
            Qb, QFb, Kb, KFb, Vtb, VFtb, km, kv, out);
    }
}